// Round 7
// baseline (271.981 us; speedup 1.0000x reference)
//
#include <hip/hip_runtime.h>

// irreps: 512x0e + 256x1o + 128x2e ; x,out: [16384, 1920] fp32, weight: 344064 fp32
// Strategy v8: v4 structure (full-K A-tile staged to LDS once, ONE barrier,
// barrier-free K-loop, B streamed at-use from L2-resident fragment-ordered wt)
// with DOUBLED M-tiles: TN=64/32/32. MFMA-per-B-load ratio 4/6/10 (was 2/3/5),
// half the wgs -> half the L2 B traffic. 2 wgs/CU (LDS 66.6KB, VGPR<=128 via
// launch_bounds(512,4)).

typedef float  f32x4  __attribute__((ext_vector_type(4)));
typedef short  bf16x8 __attribute__((ext_vector_type(8)));

#define ROWLEN 1920

__device__ __forceinline__ unsigned short f2bf(float f) {
    union { float f; unsigned int u; } c; c.f = f;
    unsigned int u = c.u;
    u += 0x7fffu + ((u >> 16) & 1u);   // round-to-nearest-even
    return (unsigned short)(u >> 16);
}

// Fragment order: element (vt, ks, lane, j) = W[ks*32 + (lane>>4)*8 + j][vt*16 + (lane&15)]
// at wt[base + ((vt*NSTEP + ks)*64 + lane)*8 + j].  Coalesced reads, scattered 2B stores.
__global__ __launch_bounds__(256) void prep_weights(const float* __restrict__ w,
                                                    unsigned short* __restrict__ wt) {
    const int g = blockIdx.x * 256 + threadIdx.x;
    if (g >= 344064) return;
    int base, lmul;
    if      (g < 262144) { base = 0;      lmul = 9; }   // mul=512
    else if (g < 327680) { base = 262144; lmul = 8; }   // mul=256
    else                 { base = 327680; lmul = 7; }   // mul=128
    const int local = g - base;
    const int u = local >> lmul;               // k index
    const int v = local & ((1 << lmul) - 1);   // output channel
    const int nstep_log = lmul - 5;            // NSTEP = mul/32
    const int vt   = v >> 4;
    const int ks   = u >> 5;
    const int lane = (((u >> 3) & 3) << 4) | (v & 15);
    const int j    = u & 7;
    wt[base + ((((vt << nstep_log) + ks) << 6) + lane) * 8 + j] = f2bf(w[g]);
}

// Logical GEMM: C[(n,i), v] = sum_u x[n,u,i] * W[u,v]
template<int MUL, int D, int TN, int X_OFF, int WT_BASE>
__device__ __forceinline__ void seg_body(const int bid,
                                         const float* __restrict__ x,
                                         const unsigned short* __restrict__ wt,
                                         float* __restrict__ out,
                                         const float scale,
                                         unsigned short* lds) {
    constexpr int KB      = 32;
    constexpr int NSTEP   = MUL / KB;
    constexpr int M_LOG   = TN * D;
    constexpr int MT      = M_LOG / 16;              // 4 / 6 / 10
    constexpr int WAVE_NT = MUL / 128;               // 4 / 2 / 1 (8 waves x 16 cols)
    constexpr int ST      = MUL + 8;
    constexpr int ROW_F4  = MUL * D / 4;
    constexpr int ITERS   = TN * ROW_F4 / 512;       // 16 / 12 / 10 (exact)
    constexpr int TVS     = NSTEP * 512;             // shorts per v-tile, frag order

    const int tid  = threadIdx.x;
    const int wave = tid >> 6;
    const int lane = tid & 63;
    const int q    = lane >> 4;
    const int t16  = lane & 15;
    const int n0   = bid * TN;

    const float* __restrict__ xblk = x + X_OFF + n0 * ROWLEN;
    const unsigned short* __restrict__ wfrag =
        wt + WT_BASE + (wave * WAVE_NT) * TVS + lane * 8;

    f32x4 acc[MT][WAVE_NT];
#pragma unroll
    for (int a = 0; a < MT; ++a)
#pragma unroll
        for (int b = 0; b < WAVE_NT; ++b) acc[a][b] = (f32x4)0.0f;

    // ---- stage FULL x-tile: fp32 -> bf16, de-interleave, K-contiguous LDS
#pragma unroll
    for (int it = 0; it < ITERS; ++it) {
        const int idx = tid + it * 512;
        const int nl  = idx / ROW_F4;            // const divisor -> magic mul
        const int c4  = (idx - nl * ROW_F4) * 4;
        const f32x4 vv = *(const f32x4*)(xblk + nl * ROWLEN + c4);
        if (D == 1) {
            unsigned int lo = (unsigned int)f2bf(vv[0]) | ((unsigned int)f2bf(vv[1]) << 16);
            unsigned int hi = (unsigned int)f2bf(vv[2]) | ((unsigned int)f2bf(vv[3]) << 16);
            unsigned int* p = (unsigned int*)&lds[nl * ST + c4];
            p[0] = lo; p[1] = hi;
        } else {
#pragma unroll
            for (int e = 0; e < 4; ++e) {
                const int c = c4 + e;
                const int u = c / D;             // const divisor
                const int i = c - u * D;
                lds[(i * TN + nl) * ST + u] = f2bf(vv[e]);
            }
        }
    }

    __syncthreads();   // the ONLY barrier

    // ---- barrier-free K loop: A frags ds_read_b128, B 2-slot rolling from L2
    bf16x8 bfr[2][WAVE_NT];
#pragma unroll
    for (int p = 0; p < 2; ++p)
#pragma unroll
        for (int tv = 0; tv < WAVE_NT; ++tv)
            bfr[p][tv] = *(const bf16x8*)&wfrag[tv * TVS + p * 512];

#pragma unroll
    for (int ks = 0; ks < NSTEP; ++ks) {
        bf16x8 afr[MT];
#pragma unroll
        for (int tm = 0; tm < MT; ++tm)
            afr[tm] = *(const bf16x8*)&lds[(16 * tm + t16) * ST + ks * KB + q * 8];
#pragma unroll
        for (int tv = 0; tv < WAVE_NT; ++tv)
#pragma unroll
            for (int tm = 0; tm < MT; ++tm)
                acc[tm][tv] = __builtin_amdgcn_mfma_f32_16x16x32_bf16(afr[tm], bfr[ks & 1][tv], acc[tm][tv], 0, 0, 0);
        if (ks + 2 < NSTEP) {
#pragma unroll
            for (int tv = 0; tv < WAVE_NT; ++tv)
                bfr[ks & 1][tv] = *(const bf16x8*)&wfrag[tv * TVS + (ks + 2) * 512];
        }
    }

    // ---- epilogue: C/D layout col=lane&15, row=q*4+r ; logical row -> (i, nl)
#pragma unroll
    for (int tm = 0; tm < MT; ++tm) {
#pragma unroll
        for (int tv = 0; tv < WAVE_NT; ++tv) {
            const int v = wave * (WAVE_NT * 16) + t16 + tv * 16;
#pragma unroll
            for (int r = 0; r < 4; ++r) {
                const int rit  = q * 4 + r;
                const int lrow = 16 * tm + rit;
                const int i    = lrow / TN;      // TN pow2 -> shift
                const int nl   = lrow - i * TN;
                out[(n0 + nl) * ROWLEN + X_OFF + v * D + i] = acc[tm][tv][r] * scale;
            }
        }
    }
}

// 1280 wgs, groups of 5: 1x seg0 (256 total) + 2x seg1 (512) + 2x seg2 (512)
__global__ __launch_bounds__(512, 4) void fused_gemm(const float* __restrict__ x,
                                                     const unsigned short* __restrict__ wt,
                                                     float* __restrict__ out) {
    extern __shared__ unsigned short lds[];
    const int b = blockIdx.x;
    const int g = b / 5;
    const int r = b - g * 5;
    if (r == 0) {
        // seg0: mul=512, d=1, TN=64 -> LDS 66560 B, MT=4 x WAVE_NT=4 (acc 64)
        seg_body<512, 1, 64, 0, 0>(g, x, wt, out, 0.044194173824f, lds);
    } else if (r <= 2) {
        // seg1: mul=256, d=3, TN=32 -> M_LOG=96, MT=6 x WAVE_NT=2 (acc 48)
        seg_body<256, 3, 32, 512, 262144>(g * 2 + (r - 1), x, wt, out, 0.0625f, lds);
    } else {
        // seg2: mul=128, d=5, TN=32 -> M_LOG=160, MT=10 x WAVE_NT=1 (acc 40)
        seg_body<128, 5, 32, 1280, 327680>(g * 2 + (r - 3), x, wt, out, 0.088388347648f, lds);
    }
}

extern "C" void kernel_launch(void* const* d_in, const int* in_sizes, int n_in,
                              void* d_out, int out_size, void* d_ws, size_t ws_size,
                              hipStream_t stream) {
    const float* x = (const float*)d_in[0];
    const float* w = (const float*)d_in[1];
    float* out = (float*)d_out;
    unsigned short* wt = (unsigned short*)d_ws;   // 344064 bf16 = 688 KB, L2-resident

    hipLaunchKernelGGL(prep_weights, dim3(1344), dim3(256), 0, stream, w, wt);
    // dynamic LDS = seg0: 64*520*2 = 66560 B -> 2 wgs/CU
    hipLaunchKernelGGL(fused_gemm, dim3(1280), dim3(512), 66560, stream, x, wt, out);
}

// Round 9
// 236.116 us; speedup vs baseline: 1.1519x; 1.1519x over previous
//
#include <hip/hip_runtime.h>

// irreps: 512x0e + 256x1o + 128x2e ; x,out: [16384, 1920] fp32, weight: 344064 fp32
// Strategy v9 (resubmit — previous round was an infra failure, no data):
// v4 structure (full-K A-tile staged once, ONE barrier, barrier-free K-loop,
// B streamed from L2-resident fragment-ordered wt) with the scheduler told NOT
// to squeeze to 64 VGPRs: amdgpu_waves_per_eu(2,4) allows ~128 VGPR live, so
// K-GROUPED B bursts (4 steps' frags loaded together) survive regalloc ->
// one L2 latency per 4 K-steps instead of per step. seg2 holds whole-K B in regs.

typedef float  f32x4  __attribute__((ext_vector_type(4)));
typedef short  bf16x8 __attribute__((ext_vector_type(8)));

#define ROWLEN 1920

__device__ __forceinline__ unsigned short f2bf(float f) {
    union { float f; unsigned int u; } c; c.f = f;
    unsigned int u = c.u;
    u += 0x7fffu + ((u >> 16) & 1u);   // round-to-nearest-even
    return (unsigned short)(u >> 16);
}

// Fragment order: element (vt, ks, lane, j) = W[ks*32 + (lane>>4)*8 + j][vt*16 + (lane&15)]
// at wt[base + ((vt*NSTEP + ks)*64 + lane)*8 + j].  Coalesced reads, scattered 2B stores.
__global__ __launch_bounds__(256) void prep_weights(const float* __restrict__ w,
                                                    unsigned short* __restrict__ wt) {
    const int g = blockIdx.x * 256 + threadIdx.x;
    if (g >= 344064) return;
    int base, lmul;
    if      (g < 262144) { base = 0;      lmul = 9; }   // mul=512
    else if (g < 327680) { base = 262144; lmul = 8; }   // mul=256
    else                 { base = 327680; lmul = 7; }   // mul=128
    const int local = g - base;
    const int u = local >> lmul;               // k index
    const int v = local & ((1 << lmul) - 1);   // output channel
    const int nstep_log = lmul - 5;            // NSTEP = mul/32
    const int vt   = v >> 4;
    const int ks   = u >> 5;
    const int lane = (((u >> 3) & 3) << 4) | (v & 15);
    const int j    = u & 7;
    wt[base + ((((vt << nstep_log) + ks) << 6) + lane) * 8 + j] = f2bf(w[g]);
}

// Logical GEMM: C[(n,i), v] = sum_u x[n,u,i] * W[u,v]
template<int MUL, int D, int TN, int X_OFF, int WT_BASE, int G>
__device__ __forceinline__ void seg_body(const int bid,
                                         const float* __restrict__ x,
                                         const unsigned short* __restrict__ wt,
                                         float* __restrict__ out,
                                         const float scale,
                                         unsigned short* lds) {
    constexpr int KB      = 32;
    constexpr int NSTEP   = MUL / KB;
    constexpr int NGRP    = NSTEP / G;
    constexpr int M_LOG   = TN * D;
    constexpr int MT      = M_LOG / 16;              // 2 / 3 / 5
    constexpr int WAVE_NT = MUL / 128;               // 4 / 2 / 1 (8 waves x 16 cols)
    constexpr int ST      = MUL + 8;
    constexpr int ROW_F4  = MUL * D / 4;
    constexpr int ITERS   = TN * ROW_F4 / 512;       // 8 / 6 / 5 (exact)
    constexpr int TVS     = NSTEP * 512;             // shorts per v-tile, frag order
    constexpr bool BREG   = (WAVE_NT * NSTEP) <= 4;  // seg2: whole-K B in 16 VGPRs

    const int tid  = threadIdx.x;
    const int wave = tid >> 6;
    const int lane = tid & 63;
    const int q    = lane >> 4;
    const int t16  = lane & 15;
    const int n0   = bid * TN;

    const float* __restrict__ xblk = x + X_OFF + n0 * ROWLEN;
    const unsigned short* __restrict__ wfrag =
        wt + WT_BASE + (wave * WAVE_NT) * TVS + lane * 8;

    f32x4 acc[MT][WAVE_NT];
#pragma unroll
    for (int a = 0; a < MT; ++a)
#pragma unroll
        for (int b = 0; b < WAVE_NT; ++b) acc[a][b] = (f32x4)0.0f;

    // ---- stage FULL x-tile: fp32 -> bf16, de-interleave, K-contiguous LDS
#pragma unroll
    for (int it = 0; it < ITERS; ++it) {
        const int idx = tid + it * 512;
        const int nl  = idx / ROW_F4;            // const divisor -> magic mul
        const int c4  = (idx - nl * ROW_F4) * 4;
        const f32x4 vv = *(const f32x4*)(xblk + nl * ROWLEN + c4);
        if (D == 1) {
            unsigned int lo = (unsigned int)f2bf(vv[0]) | ((unsigned int)f2bf(vv[1]) << 16);
            unsigned int hi = (unsigned int)f2bf(vv[2]) | ((unsigned int)f2bf(vv[3]) << 16);
            unsigned int* p = (unsigned int*)&lds[nl * ST + c4];
            p[0] = lo; p[1] = hi;
        } else {
#pragma unroll
            for (int e = 0; e < 4; ++e) {
                const int c = c4 + e;
                const int u = c / D;             // const divisor
                const int i = c - u * D;
                lds[(i * TN + nl) * ST + u] = f2bf(vv[e]);
            }
        }
    }

    __syncthreads();   // the ONLY barrier

    if constexpr (BREG) {
        // ---- seg2: whole-K B panel = 4 frags (16 VGPR), pure LDS+MFMA loop
        bf16x8 breg[WAVE_NT * NSTEP];
#pragma unroll
        for (int tv = 0; tv < WAVE_NT; ++tv)
#pragma unroll
            for (int ks = 0; ks < NSTEP; ++ks)
                breg[tv * NSTEP + ks] = *(const bf16x8*)&wfrag[tv * TVS + ks * 512];
#pragma unroll
        for (int ks = 0; ks < NSTEP; ++ks) {
            bf16x8 afr[MT];
#pragma unroll
            for (int tm = 0; tm < MT; ++tm)
                afr[tm] = *(const bf16x8*)&lds[(16 * tm + t16) * ST + ks * KB + q * 8];
#pragma unroll
            for (int tv = 0; tv < WAVE_NT; ++tv)
#pragma unroll
                for (int tm = 0; tm < MT; ++tm)
                    acc[tm][tv] = __builtin_amdgcn_mfma_f32_16x16x32_bf16(afr[tm], breg[tv * NSTEP + ks], acc[tm][tv], 0, 0, 0);
        }
    } else {
        // ---- K-grouped: burst-load G steps' B frags, then G steps of ds_read+MFMA
#pragma unroll
        for (int g = 0; g < NGRP; ++g) {
            bf16x8 bgrp[G][WAVE_NT];
#pragma unroll
            for (int jg = 0; jg < G; ++jg)
#pragma unroll
                for (int tv = 0; tv < WAVE_NT; ++tv)
                    bgrp[jg][tv] = *(const bf16x8*)&wfrag[tv * TVS + (g * G + jg) * 512];
#pragma unroll
            for (int jg = 0; jg < G; ++jg) {
                const int ks = g * G + jg;
                bf16x8 afr[MT];
#pragma unroll
                for (int tm = 0; tm < MT; ++tm)
                    afr[tm] = *(const bf16x8*)&lds[(16 * tm + t16) * ST + ks * KB + q * 8];
#pragma unroll
                for (int tv = 0; tv < WAVE_NT; ++tv)
#pragma unroll
                    for (int tm = 0; tm < MT; ++tm)
                        acc[tm][tv] = __builtin_amdgcn_mfma_f32_16x16x32_bf16(afr[tm], bgrp[jg][tv], acc[tm][tv], 0, 0, 0);
            }
        }
    }

    // ---- epilogue: C/D layout col=lane&15, row=q*4+r ; logical row -> (i, nl)
#pragma unroll
    for (int tm = 0; tm < MT; ++tm) {
#pragma unroll
        for (int tv = 0; tv < WAVE_NT; ++tv) {
            const int v = wave * (WAVE_NT * 16) + t16 + tv * 16;
#pragma unroll
            for (int r = 0; r < 4; ++r) {
                const int rit  = q * 4 + r;
                const int lrow = 16 * tm + rit;
                const int i    = lrow / TN;      // TN pow2 -> shift
                const int nl   = lrow - i * TN;
                out[(n0 + nl) * ROWLEN + X_OFF + v * D + i] = acc[tm][tv][r] * scale;
            }
        }
    }
}

// 2560 wgs, groups of 5: 1x seg0 + 2x seg1 + 2x seg2 (load-balanced interleave)
__global__ __launch_bounds__(512)
__attribute__((amdgpu_waves_per_eu(2, 4)))           // cap occupancy target at 4/EU:
void fused_gemm(const float* __restrict__ x,         // scheduler may hold ~128 VGPR
                const unsigned short* __restrict__ wt,
                float* __restrict__ out) {
    extern __shared__ unsigned short lds[];
    const int b = blockIdx.x;
    const int g = b / 5;
    const int r = b - g * 5;
    if (r == 0) {
        // seg0: mul=512, d=1, TN=32, G=4 -> bgrp 64 + acc 32 + afr 8 ~ 116 VGPR
        seg_body<512, 1, 32, 0, 0, 4>(g, x, wt, out, 0.044194173824f, lds);
    } else if (r <= 2) {
        // seg1: mul=256, d=3, TN=16, G=4 -> bgrp 32 + acc 24 ~ 85 VGPR
        seg_body<256, 3, 16, 512, 262144, 4>(g * 2 + (r - 1), x, wt, out, 0.0625f, lds);
    } else {
        // seg2: mul=128, d=5, TN=16 -> whole-K B in regs (16), acc 20 ~ 60 VGPR
        seg_body<128, 5, 16, 1280, 327680, 4>(g * 2 + (r - 3), x, wt, out, 0.088388347648f, lds);
    }
}

extern "C" void kernel_launch(void* const* d_in, const int* in_sizes, int n_in,
                              void* d_out, int out_size, void* d_ws, size_t ws_size,
                              hipStream_t stream) {
    const float* x = (const float*)d_in[0];
    const float* w = (const float*)d_in[1];
    float* out = (float*)d_out;
    unsigned short* wt = (unsigned short*)d_ws;   // 344064 bf16 = 688 KB, L2-resident

    hipLaunchKernelGGL(prep_weights, dim3(1344), dim3(256), 0, stream, w, wt);
    // dynamic LDS = seg0: 32*520*2 = 33280 B -> 2 wgs/CU at the 4-waves/EU target
    hipLaunchKernelGGL(fused_gemm, dim3(2560), dim3(512), 33280, stream, x, wt, out);
}